// Round 6
// baseline (142.191 us; speedup 1.0000x reference)
//
#include <hip/hip_runtime.h>
#include <math.h>

#define IMG 512
#define TW 128     // output tile width
#define TH 16      // output tile height
#define RS 150     // LDS row stride floats: 150%32=22, gcd(22,32)=2 -> 16 rows cover all
                   // 16 even bank residues exactly once (h-read conflict killer, round 5)
#define NQ 36      // col-quads per intermediate row (cols x0-8 .. x0+135; halo = 2 full quads/side)
#define MMB 1024   // minmax stage-1 blocks

struct W11 { float w[11]; };

__device__ __forceinline__ unsigned omap(float f) {
  unsigned b = __float_as_uint(f);
  return (b & 0x80000000u) ? ~b : (b | 0x80000000u);
}
__device__ __forceinline__ float ounmap(unsigned u) {
  return __uint_as_float((u & 0x80000000u) ? (u ^ 0x80000000u) : ~u);
}

// Stage 1: per-block partial min/max -> disjoint slots, no atomics.
__global__ __launch_bounds__(256) void minmax_part(const float4* __restrict__ img,
                                                   int n4, unsigned* __restrict__ part) {
  unsigned mx = 0u, mn = 0xFFFFFFFFu;
  int stride = gridDim.x * blockDim.x;
  for (int i = blockIdx.x * blockDim.x + threadIdx.x; i < n4; i += stride) {
    float4 v = img[i];
    unsigned a = omap(v.x), b = omap(v.y), c = omap(v.z), d = omap(v.w);
    mx = max(mx, max(max(a, b), max(c, d)));
    mn = min(mn, min(min(a, b), min(c, d)));
  }
  #pragma unroll
  for (int off = 32; off > 0; off >>= 1) {
    mx = max(mx, __shfl_down(mx, off));
    mn = min(mn, __shfl_down(mn, off));
  }
  __shared__ unsigned smx[4], smn[4];
  int lane = threadIdx.x & 63, wv = threadIdx.x >> 6;
  if (lane == 0) { smx[wv] = mx; smn[wv] = mn; }
  __syncthreads();
  if (threadIdx.x == 0) {
    mx = max(max(smx[0], smx[1]), max(smx[2], smx[3]));
    mn = min(min(smn[0], smn[1]), min(smn[2], smn[3]));
    part[2 * blockIdx.x]     = mx;
    part[2 * blockIdx.x + 1] = mn;
  }
}

// Stage 2: fold MMB partial pairs into ws[0]=max, ws[1]=min.
__global__ __launch_bounds__(256) void minmax_final(const unsigned* __restrict__ part,
                                                    unsigned* __restrict__ ws) {
  unsigned mx = 0u, mn = 0xFFFFFFFFu;
  for (int i = threadIdx.x; i < MMB; i += 256) {
    mx = max(mx, part[2 * i]);
    mn = min(mn, part[2 * i + 1]);
  }
  #pragma unroll
  for (int off = 32; off > 0; off >>= 1) {
    mx = max(mx, __shfl_down(mx, off));
    mn = min(mn, __shfl_down(mn, off));
  }
  __shared__ unsigned smx[4], smn[4];
  int lane = threadIdx.x & 63, wv = threadIdx.x >> 6;
  if (lane == 0) { smx[wv] = mx; smn[wv] = mn; }
  __syncthreads();
  if (threadIdx.x == 0) {
    ws[0] = max(max(smx[0], smx[1]), max(smx[2], smx[3]));
    ws[1] = min(min(smn[0], smn[1]), min(smn[2], smn[3]));
  }
}

// One vertical task: 11-tap v-conv of {a, b, a^2+b^2, a*b} for (1 row x 4 cols).
// Round-6 change: BATCH-LOAD all 11 rows of both images into NAMED float4
// registers up front (MLP 22 instead of ~3). Round-5 profile showed every pipe
// <=44% busy -> load-latency-bound; VGPR headroom (60 used / 128 cap) is the
// free resource. Named vars only (a0..a10,b0..b10) -- the SROA-proof pattern
// (rounds 1/3 lesson: anything the compiler can't fully scalarize goes to
// scratch and costs 100s of MB of stack traffic).
__device__ __forceinline__ void vtask(int t, int x0, int y0, bool y_full,
                                      const float* __restrict__ p1,
                                      const float* __restrict__ p2,
                                      const W11& wv,
                                      float (*V)[TH][RS]) {
  const int r = t / NQ;              // 0..15
  const int q = t - r * NQ;          // 0..35
  const int gx0 = x0 - 8 + 4 * q;    // multiple of 4; halo quads are fully OOB
  const int gy0 = y0 + r - 5;

  float4 a0, a1, a2, a3, a4, a5, a6, a7, a8, a9, a10;
  float4 b0, b1, b2, b3, b4, b5, b6, b7, b8, b9, b10;

#define ZROW(ak, bk) { ak = make_float4(0.f, 0.f, 0.f, 0.f); bk = make_float4(0.f, 0.f, 0.f, 0.f); }
#define FROW(k, ak, bk) { ak = A[(k) * (IMG / 4)]; bk = B[(k) * (IMG / 4)]; }
#define GROW(k, ak, bk) { int row = gy0 + (k);                                \
    if ((unsigned)row < IMG) {                                                \
      ak = *(const float4*)(p1 + (size_t)row * IMG + gx0);                    \
      bk = *(const float4*)(p2 + (size_t)row * IMG + gx0);                    \
    } else ZROW(ak, bk) }

  if ((unsigned)gx0 < IMG) {
    if (y_full) {
      const float4* A = (const float4*)(p1 + (size_t)gy0 * IMG + gx0);
      const float4* B = (const float4*)(p2 + (size_t)gy0 * IMG + gx0);
      FROW(0, a0, b0)  FROW(1, a1, b1)  FROW(2, a2, b2)  FROW(3, a3, b3)
      FROW(4, a4, b4)  FROW(5, a5, b5)  FROW(6, a6, b6)  FROW(7, a7, b7)
      FROW(8, a8, b8)  FROW(9, a9, b9)  FROW(10, a10, b10)
    } else {
      GROW(0, a0, b0)  GROW(1, a1, b1)  GROW(2, a2, b2)  GROW(3, a3, b3)
      GROW(4, a4, b4)  GROW(5, a5, b5)  GROW(6, a6, b6)  GROW(7, a7, b7)
      GROW(8, a8, b8)  GROW(9, a9, b9)  GROW(10, a10, b10)
    }
  } else {
    ZROW(a0, b0)  ZROW(a1, b1)  ZROW(a2, b2)  ZROW(a3, b3)  ZROW(a4, b4)
    ZROW(a5, b5)  ZROW(a6, b6)  ZROW(a7, b7)  ZROW(a8, b8)  ZROW(a9, b9)
    ZROW(a10, b10)
  }
#undef ZROW
#undef FROW
#undef GROW

  float c0x = 0.f, c0y = 0.f, c0z = 0.f, c0w = 0.f;   // mu1
  float c1x = 0.f, c1y = 0.f, c1z = 0.f, c1w = 0.f;   // mu2
  float c2x = 0.f, c2y = 0.f, c2z = 0.f, c2w = 0.f;   // a^2+b^2
  float c3x = 0.f, c3y = 0.f, c3z = 0.f, c3w = 0.f;   // a*b

#define VSTEP(k, a, b)                                                        \
  {                                                                           \
    float wk = wv.w[k];                                                       \
    c0x += wk * a.x; c0y += wk * a.y; c0z += wk * a.z; c0w += wk * a.w;       \
    c1x += wk * b.x; c1y += wk * b.y; c1z += wk * b.z; c1w += wk * b.w;       \
    float sx = a.x * a.x + b.x * b.x, sy = a.y * a.y + b.y * b.y;             \
    float sz = a.z * a.z + b.z * b.z, sw = a.w * a.w + b.w * b.w;             \
    c2x += wk * sx; c2y += wk * sy; c2z += wk * sz; c2w += wk * sw;           \
    float px = a.x * b.x, py = a.y * b.y, pz = a.z * b.z, pw = a.w * b.w;     \
    c3x += wk * px; c3y += wk * py; c3z += wk * pz; c3w += wk * pw;           \
  }

  VSTEP(0, a0, b0)   VSTEP(1, a1, b1)   VSTEP(2, a2, b2)   VSTEP(3, a3, b3)
  VSTEP(4, a4, b4)   VSTEP(5, a5, b5)   VSTEP(6, a6, b6)   VSTEP(7, a7, b7)
  VSTEP(8, a8, b8)   VSTEP(9, a9, b9)   VSTEP(10, a10, b10)
#undef VSTEP

  // b64 writes, consecutive lanes -> consecutive addresses (clean class).
  // Stores end accumulator liveness.
  *(float2*)&V[0][r][4 * q]     = make_float2(c0x, c0y);
  *(float2*)&V[0][r][4 * q + 2] = make_float2(c0z, c0w);
  *(float2*)&V[1][r][4 * q]     = make_float2(c1x, c1y);
  *(float2*)&V[1][r][4 * q + 2] = make_float2(c1z, c1w);
  *(float2*)&V[2][r][4 * q]     = make_float2(c2x, c2y);
  *(float2*)&V[2][r][4 * q + 2] = make_float2(c2z, c2w);
  *(float2*)&V[3][r][4 * q]     = make_float2(c3x, c3y);
  *(float2*)&V[3][r][4 * q + 2] = make_float2(c3z, c3w);
}

// Fused SSIM, v-first, phase-balanced, b64-only LDS, conflict-free-ish.
// launch_bounds(512,4): 128-VGPR cap -- proven spill-free regime; batch-load
// needs ~115 VGPR (88 load + 16 acc + addressing). 2 blocks/CU co-resident;
// the two blocks overlap complementary phases (v-pass: VMEM+VALU, h-pass: LDS).
__global__ __launch_bounds__(512, 4) void ssim_k(const float* __restrict__ img1,
                                                 const float* __restrict__ img2,
                                                 float* __restrict__ out,
                                                 const unsigned* __restrict__ ws,
                                                 W11 wv) {
  __shared__ float V[4][TH][RS];   // 38400 B

  const int tid = threadIdx.x;
  const int bx = blockIdx.x, by = blockIdx.y, n = blockIdx.z;
  const float* p1 = img1 + (size_t)n * IMG * IMG;
  const float* p2 = img2 + (size_t)n * IMG * IMG;
  const int x0 = bx * TW;
  const int y0 = by * TH;

  // C1/C2 (scalar loads issued early; needed after the barrier)
  float L = ounmap(ws[0]) - ounmap(ws[1]);
  if (L == 0.f) L = 5.f;
  float C1 = 0.01f * L; C1 *= C1;
  float C2 = 0.03f * L; C2 *= C2;

  const bool y_full = (by > 0) & (by < IMG / TH - 1);

  // ---- vertical pass: 576 tasks on 512 threads. Everyone does task tid;
  // wave 0 (full 64-lane density) does the 64 extras in a separate branch
  // AFTER the first task's stores (separate liveness region).
  vtask(tid, x0, y0, y_full, p1, p2, wv, V);
  if (tid < 64) vtask(512 + tid, x0, y0, y_full, p1, p2, wv, V);

  __syncthreads();   // the only barrier

  // ---- horizontal pass: all 512 threads, thread = (1 row, 4 output cols).
  // Mapping r = tid&15 + RS=150: every b64 read hits each bank exactly twice
  // (round-5 verified: conflicts 14.8M -> 5.2M, remainder is v-write residue).
  {
    const int r  = tid & 15;           // row 0..15
    const int c4 = (tid >> 4) << 2;    // output col offset 0..124

    float acc[4][4];
    #pragma unroll
    for (int f = 0; f < 4; ++f)
      #pragma unroll
      for (int c = 0; c < 4; ++c) acc[f][c] = 0.f;

    float v[16];   // function scope, constant indices only (SROA-safe)
    #pragma unroll
    for (int f = 0; f < 4; ++f) {
      // window: intermediate local cols c4+2 .. c4+17; taps use c4+3 .. c4+16
      const float* row = &V[f][r][c4 + 2];
      float2 g0 = *(const float2*)(row + 0);
      float2 g1 = *(const float2*)(row + 2);
      float2 g2 = *(const float2*)(row + 4);
      float2 g3 = *(const float2*)(row + 6);
      float2 g4 = *(const float2*)(row + 8);
      float2 g5 = *(const float2*)(row + 10);
      float2 g6 = *(const float2*)(row + 12);
      float2 g7 = *(const float2*)(row + 14);
      v[0]  = g0.x; v[1]  = g0.y; v[2]  = g1.x; v[3]  = g1.y;
      v[4]  = g2.x; v[5]  = g2.y; v[6]  = g3.x; v[7]  = g3.y;
      v[8]  = g4.x; v[9]  = g4.y; v[10] = g5.x; v[11] = g5.y;
      v[12] = g6.x; v[13] = g6.y; v[14] = g7.x; v[15] = g7.y;
      // output col c taps v[c+1+k], k=0..10  (v[i] = local col c4+2+i)
      #pragma unroll
      for (int k = 0; k < 11; ++k) {
        float wk = wv.w[k];
        #pragma unroll
        for (int c = 0; c < 4; ++c) acc[f][c] += wk * v[c + 1 + k];
      }
    }

    float res[4];
    #pragma unroll
    for (int c = 0; c < 4; ++c) {
      float mu1 = acc[0][c], mu2 = acc[1][c];
      float mu1s = mu1 * mu1, mu2s = mu2 * mu2, mu12 = mu1 * mu2;
      float sS  = acc[2][c] - mu1s - mu2s;   // sigma1_sq + sigma2_sq
      float s12 = acc[3][c] - mu12;
      float num = (2.f * mu12 + C1) * (2.f * s12 + C2);
      float den = (mu1s + mu2s + C1) * (sS + C2);
      res[c] = num / den;
    }
    float* op = out + (size_t)n * IMG * IMG + (size_t)(y0 + r) * IMG + x0 + c4;
    *(float4*)op = make_float4(res[0], res[1], res[2], res[3]);
  }
}

extern "C" void kernel_launch(void* const* d_in, const int* in_sizes, int n_in,
                              void* d_out, int out_size, void* d_ws, size_t ws_size,
                              hipStream_t stream) {
  const float* img1 = (const float*)d_in[0];
  const float* img2 = (const float*)d_in[1];
  float* out = (float*)d_out;
  unsigned* ws = (unsigned*)d_ws;          // [0..1]: final max/min; [16..]: partials
  unsigned* part = ws + 16;
  int n = in_sizes[0];             // 32*1*512*512
  int batch = n / (IMG * IMG);     // 32

  // Gaussian window, center at ws/2 = 5.5 (asymmetric!), normalized
  W11 wv;
  double g[11], s = 0.0;
  for (int i = 0; i < 11; ++i) { double d = i - 5.5; g[i] = exp(-(d * d) / 4.5); s += g[i]; }
  for (int i = 0; i < 11; ++i) wv.w[i] = (float)(g[i] / s);

  minmax_part<<<MMB, 256, 0, stream>>>((const float4*)img1, n / 4, part);
  minmax_final<<<1, 256, 0, stream>>>(part, ws);
  dim3 grid(IMG / TW, IMG / TH, batch);
  ssim_k<<<grid, 512, 0, stream>>>(img1, img2, out, ws, wv);
}